// Round 13
// baseline (67.162 us; speedup 1.0000x reference)
//
#include <hip/hip_runtime.h>
#include <hip/hip_fp16.h>
#include <math.h>

#define HWPX 262144   // 512*512
#define NIMG 8
#define ACC_STRIDE 96
#define NB 1024       // histogram bins (e-space for P, z-space for Q)
#define ZMAX 8.0f
#define NSPLIT 32
#define NGRP 2
#define PREP_BLOCKS 512   // 64 blocks/image, 1024 thr, 4 px/thread scalar -> 2 blocks/CU
// accd layout per image (doubles):
// [80] bg_seed, [81] fit_seed(acc), [82] inst_loss(acc), [83] var_loss, [84] obj

typedef unsigned long long u64;

__device__ __forceinline__ float tanh_fast(float x) {
  float t = __expf(2.0f * x);
  return 1.0f - __fdividef(2.0f, t + 1.0f);
}
__device__ __forceinline__ float sigmoid_fast(float x) {
  return __fdividef(1.0f, 1.0f + __expf(-x));
}

// ---------- pass 1: stats + packed records; 1024-thr, scalar loads, 2 blocks/CU ----------
template<bool PACK>
__global__ __launch_bounds__(1024) void k_prep(const float* __restrict__ pred,
    const int* __restrict__ inst, const int* __restrict__ lab,
    u64* __restrict__ rec, float* __restrict__ part)
{
  __shared__ float s[8][83];   // 8 replicas, stride 83 (coprime with 32 banks)
  int t = threadIdx.x;
  for (int i = t; i < 8*83; i += 1024) (&s[0][0])[i] = 0.0f;
  __syncthreads();
  int bid = blockIdx.x;
  int b = bid >> 6;                 // 64 blocks per image
  int chunk = bid & 63;             // 4096 px per block
  const float* pb = pred + (size_t)b*4*HWPX;
  size_t ib = (size_t)b*HWPX;
  int r = t & 7;
  float bg = 0.0f;
  #pragma unroll
  for (int j = 0; j < 4; ++j) {
    int px = (chunk << 12) + (j << 10) + t;
    float X = pb[px];
    float Y = pb[HWPX + px];
    float Gv = pb[2*HWPX + px];
    float Q = pb[3*HWPX + px];
    int L = lab[ib + px];
    int I = inst[ib + px];
    int w = px & 511, h = px >> 9;
    float xm = (float)w * (1.0f/1023.0f), ym = (float)h * (1.0f/1023.0f);
    float sd = sigmoid_fast(Q);
    int mid = (L == 1 && (unsigned)(I-1) < 16u) ? I : 0;
    if (PACK) {
      float ex = tanh_fast(X) + xm;
      float ey = tanh_fast(Y) + ym;
      rec[ib + px] = (u64)__half_as_ushort(__float2half(ex))
                   | ((u64)__half_as_ushort(__float2half(ey)) << 16)
                   | ((u64)__half_as_ushort(__float2half(sd)) << 32)
                   | ((u64)mid << 48);
    }
    if (L == 0) {
      bg += sd*sd;
    } else if (mid) {
      int k = mid - 1;
      atomicAdd(&s[r][k], 1.0f);
      atomicAdd(&s[r][16+k], xm);
      atomicAdd(&s[r][32+k], ym);
      atomicAdd(&s[r][48+k], Gv);
      atomicAdd(&s[r][64+k], Gv*Gv);
    }
  }
  #pragma unroll
  for (int o = 32; o > 0; o >>= 1) bg += __shfl_down(bg, o);
  if ((t & 63) == 0) atomicAdd(&s[0][80], bg);
  __syncthreads();
  if (t < 96) {
    float v = 0.0f;
    if (t < 81) {
      #pragma unroll
      for (int rr = 0; rr < 8; ++rr) v += s[rr][t];
    }
    part[(size_t)bid*96 + t] = v;
  }
}

// ---------- pass 1b: reduce 64 partials/image, finalize pairinfo + accd ----------
__global__ __launch_bounds__(128) void k_fin(const float* __restrict__ part,
    double* __restrict__ accd, float* __restrict__ pairinfo)
{
  __shared__ float red[96];
  int t = threadIdx.x, b = blockIdx.x;
  if (t < 96) {
    float v = 0.0f;
    const float* pp = part + (size_t)b*64*96 + t;
    #pragma unroll 8
    for (int blk = 0; blk < 64; ++blk) v += pp[(size_t)blk*96];
    red[t] = v;
  }
  __syncthreads();
  if (t < 16) {
    float cnt = red[t];
    float safe = cnt > 0.0f ? cnt : 1.0f;
    float sm = red[48+t] / safe;
    float4 pi = make_float4(red[16+t]/safe, red[32+t]/safe, __expf(10.0f*sm), cnt);
    ((float4*)pairinfo)[b*16 + t] = pi;
  }
  if (t == 0) {
    double vs = 0.0; float np = 0.0f;
    for (int k2 = 0; k2 < 16; ++k2) {
      float cnt = red[k2];
      if (cnt > 0.0f) {
        np += 1.0f;
        float ssg = red[48+k2];
        float var = (red[64+k2] - ssg*ssg/cnt) / cnt;
        if (var < 0.0f) var = 0.0f;
        vs += (double)var;
      }
    }
    double* ab = accd + (size_t)b*ACC_STRIDE;
    ab[80] = (double)red[80];
    ab[81] = 0.0;
    ab[82] = 0.0;
    ab[83] = vs;
    ab[84] = np > 1.0f ? (double)np : 1.0;
  }
}

// ---------- pass 2: 8-inst histograms, scalar rec loads, 8-iter loop, 2 blocks/CU ----------
__global__ __launch_bounds__(1024) void k_hist(const u64* __restrict__ rec,
    const float* __restrict__ pairinfo,
    unsigned* __restrict__ partial, double* __restrict__ accd)
{
  __shared__ unsigned hist[8*NB];   // 32 KB, P<<16 at e-bin, Q at z-bin
  __shared__ float redf[16];
  int t = threadIdx.x, bid = blockIdx.x;
  int b = bid & 7;                  // XCD-local image
  int rr = bid >> 3;
  int g = rr & 1;                   // instance group
  int s = rr >> 1;                  // pixel split 0..31
  for (int i = t; i < 8*NB; i += 1024) hist[i] = 0u;
  float cx[8], cy[8], se[8], s128[8];
  #pragma unroll
  for (int j = 0; j < 8; ++j) {
    float4 pi = ((const float4*)pairinfo)[b*16 + g*8 + j];
    cx[j] = pi.x; cy[j] = pi.y; se[j] = pi.z; s128[j] = pi.z * ((float)NB/ZMAX);
  }
  __syncthreads();
  size_t base = (size_t)b*HWPX + (size_t)s*(HWPX/NSPLIT);
  float fit = 0.0f;
  #pragma unroll 2
  for (int it = 0; it < HWPX/NSPLIT/1024; ++it) {   // 8 iterations, scalar u64
    size_t px = base + it*1024 + t;
    u64 v = rec[px];
    float ex = __half2float(__ushort_as_half((unsigned short)(v & 0xffffu)));
    float ey = __half2float(__ushort_as_half((unsigned short)((v >> 16) & 0xffffu)));
    float sd = __half2float(__ushort_as_half((unsigned short)((v >> 32) & 0xffffu)));
    int rel = (int)(v >> 48) - 1 - g*8;
    #pragma unroll
    for (int j = 0; j < 8; ++j) {
      float dx = ex - cx[j], dy = ey - cy[j];
      float d2 = fmaf(dx, dx, dy*dy);
      int key; unsigned add;
      if (rel == j) {                       // positive (rare)
        float d = __expf(-d2 * se[j]);
        float e = fmaf(-2.0f, d, 2.0f);
        int kk = (int)(e * (float)(NB/2));
        key = kk > NB-1 ? NB-1 : kk;
        add = 0x10000u;
        float df = sd - d; fit += df*df;
      } else {                              // negative: z-bin, no exp
        key = (int)fminf(d2 * s128[j], (float)(NB-1));
        add = 1u;
      }
      atomicAdd(&hist[j*NB + key], add);
    }
  }
  #pragma unroll
  for (int o = 32; o > 0; o >>= 1) fit += __shfl_down(fit, o);
  if ((t & 63) == 0) redf[t >> 6] = fit;
  __syncthreads();
  if (t == 0) {
    float ft = 0.0f;
    for (int i = 0; i < 16; ++i) ft += redf[i];
    atomicAdd(&accd[(size_t)b*ACC_STRIDE + 81], (double)ft);
  }
  unsigned* pp = partial + (size_t)((b*NGRP + g)*NSPLIT + s)*(8*NB);
  for (int i = t; i < 8*NB; i += 1024) pp[i] = hist[i];
}

// ---------- pass 3: merge partials, z->e, descending scan + Lovasz integral ----------
__global__ __launch_bounds__(1024) void k_scan(const unsigned* __restrict__ partial,
    const float* __restrict__ pairinfo, double* __restrict__ accd)
{
  __shared__ unsigned sp[NB], sq[NB];
  __shared__ float red[16];
  int t = threadIdx.x, bid = blockIdx.x;
  int b = bid >> 4, k = bid & 15;
  int g = k >> 3, j8 = k & 7;
  float G = pairinfo[(b*16 + k)*4 + 3];
  if (G <= 0.0f) return;   // absent instance (uniform block exit)
  sq[t] = 0u;
  __syncthreads();
  unsigned p = 0, q = 0;
  const unsigned* basep = partial + (size_t)((b*NGRP + g)*NSPLIT)*(8*NB) + j8*NB + t;
  #pragma unroll 4
  for (int s2 = 0; s2 < NSPLIT; ++s2) {
    unsigned h = basep[(size_t)s2*(8*NB)];
    p += h >> 16; q += h & 0xffffu;
  }
  // q is a z-bin count: convert to e-bin (e = 2*exp(-z_mid))
  float zmid = (t + 0.5f) * (ZMAX/NB);
  float ev = 2.0f * __expf(-zmid);
  int eb = (int)(ev * (float)(NB/2));
  if (eb > NB-1) eb = NB-1;
  if (q) atomicAdd(&sq[eb], q);
  __syncthreads();
  unsigned qe = sq[t];
  __syncthreads();
  int j = (NB-1) - t;          // descending-e rank
  sp[j] = p; sq[j] = qe;
  __syncthreads();
  for (int off = 1; off < NB; off <<= 1) {
    unsigned vp = 0, vq = 0;
    if (j >= off) { vp = sp[j-off]; vq = sq[j-off]; }
    __syncthreads();
    sp[j] += vp; sq[j] += vq;
    __syncthreads();
  }
  float A  = (float)(sp[j] - p);    // positives strictly above my e-bin
  float Bn = (float)(sq[j] - qe);   // negatives strictly above my e-bin
  float val = (t + 0.5f) * (2.0f/NB);
  float pf = (float)p, qf = (float)qe;
  float Jb = (A + Bn) / (G + Bn);
  float Ja = (A + Bn + pf + qf) / (G + Bn + qf);
  float contrib = val * (Ja - Jb);
  #pragma unroll
  for (int o = 32; o > 0; o >>= 1) contrib += __shfl_down(contrib, o);
  if ((t & 63) == 0) red[t >> 6] = contrib;
  __syncthreads();
  if (t == 0) {
    float tot = 0.0f;
    for (int i = 0; i < 16; ++i) tot += red[i];
    atomicAdd(&accd[(size_t)b*ACC_STRIDE + 82], (double)tot);
  }
}

// ---------- fallback: proven round-1 kernel (recompute path, SHIFT=18) ----------
__global__ __launch_bounds__(1024) void k_lov_old(const float* __restrict__ pred,
    const int* __restrict__ inst, const int* __restrict__ lab,
    const float* __restrict__ pairinfo, double* __restrict__ accd)
{
  constexpr int SHIFT = 18;
  constexpr int NBB = (0x40000000 >> SHIFT) + 1;
  extern __shared__ unsigned char smem[];
  unsigned* histP = reinterpret_cast<unsigned*>(smem);
  unsigned* histQ = histP + NBB;
  unsigned* scanP = histQ + NBB;
  unsigned* scanQ = scanP + 1024;
  float* red  = reinterpret_cast<float*>(scanQ + 1024);
  float* redf = red + 16;
  int t = threadIdx.x, bid = blockIdx.x;
  int b = bid >> 4, k = bid & 15;
  float4 pi = reinterpret_cast<const float4*>(pairinfo)[bid];
  float cx = pi.x, cy = pi.y, sexp = pi.z, G = pi.w;
  if (G <= 0.0f) return;
  for (int i = t; i < 2*NBB; i += 1024) histP[i] = 0u;
  __syncthreads();
  size_t ib = (size_t)b * HWPX;
  const float* pb = pred + (size_t)b * 4 * HWPX;
  const int target = k + 1;
  float fit = 0.0f;
  for (int j = 0; j < HWPX/1024; ++j) {
    int px = (j << 10) + t;
    int h = px >> 9, w = px & 511;
    float ex = tanhf(pb[px]) + w*(1.0f/1023.0f);
    float ey = tanhf(pb[HWPX+px]) + h*(1.0f/1023.0f);
    float sd = 1.0f/(1.0f + __expf(-pb[3*HWPX+px]));
    int lv = lab[ib+px], iv = inst[ib+px];
    float dx = ex - cx, dy = ey - cy;
    float d = __expf(-sexp * (dx*dx + dy*dy));
    bool m = (lv == 1) && (iv == target);
    float e = m ? fmaf(-2.0f, d, 2.0f) : 2.0f * d;
    unsigned key = __float_as_uint(e) >> SHIFT;
    atomicAdd(m ? &histP[key] : &histQ[key], 1u);
    if (m) { float df = sd - d; fit += df*df; }
  }
  #pragma unroll
  for (int o = 32; o > 0; o >>= 1) fit += __shfl_down(fit, o);
  if ((t & 63) == 0) redf[t >> 6] = fit;
  __syncthreads();
  constexpr int CB = NBB / 1024;
  int start = (NBB - 1) - t * CB;
  int nk = (t == 1023) ? (CB + 1) : CB;
  unsigned lp = 0, lq = 0;
  for (int i = 0; i < nk; ++i) { lp += histP[start-i]; lq += histQ[start-i]; }
  scanP[t] = lp; scanQ[t] = lq;
  __syncthreads();
  for (int off = 1; off < 1024; off <<= 1) {
    unsigned vp = 0, vq = 0;
    if (t >= off) { vp = scanP[t-off]; vq = scanQ[t-off]; }
    __syncthreads();
    scanP[t] += vp; scanQ[t] += vq;
    __syncthreads();
  }
  float A  = (float)(scanP[t] - lp);
  float Bn = (float)(scanQ[t] - lq);
  float contrib = 0.0f;
  for (int i = 0; i < nk; ++i) {
    int kk = start - i;
    unsigned p = histP[kk], q = histQ[kk];
    if (p | q) {
      float lo = __uint_as_float((unsigned)kk << SHIFT);
      float hi = __uint_as_float((unsigned)(kk+1) << SHIFT);
      float valv = 0.5f*(lo+hi);
      if (valv > 2.0f) valv = 2.0f;
      float pq = (float)(p + q), qf = (float)q;
      float Jb = (A + Bn) / (G + Bn);
      float Ja = (A + Bn + pq) / (G + Bn + qf);
      contrib += valv * (Ja - Jb);
      A += (float)p; Bn += qf;
    }
  }
  #pragma unroll
  for (int o = 32; o > 0; o >>= 1) contrib += __shfl_down(contrib, o);
  if ((t & 63) == 0) red[t >> 6] = contrib;
  __syncthreads();
  if (t == 0) {
    float tot = 0.0f, ft = 0.0f;
    for (int i = 0; i < 16; ++i) { tot += red[i]; ft += redf[i]; }
    atomicAdd(&accd[(size_t)b*ACC_STRIDE + 82], (double)tot);
    atomicAdd(&accd[(size_t)b*ACC_STRIDE + 81], (double)ft);
  }
}

__global__ void k_final(const double* __restrict__ accd, float* __restrict__ out)
{
  int t = threadIdx.x;
  double lb = 0.0;
  if (t < NIMG) {
    const double* ab = accd + (size_t)t*ACC_STRIDE;
    lb = (ab[82] + 10.0*ab[83]) / ab[84] + (ab[80] + ab[81]) * (1.0/(double)HWPX);
  }
  #pragma unroll
  for (int o = 4; o > 0; o >>= 1) lb += __shfl_down(lb, o);
  if (t == 0) out[0] = (float)(lb * 0.125);
}

extern "C" void kernel_launch(void* const* d_in, const int* in_sizes, int n_in,
                              void* d_out, int out_size, void* d_ws, size_t ws_size,
                              hipStream_t stream)
{
  const float* pred = (const float*)d_in[0];
  const int*   inst = (const int*)d_in[1];
  const int*   lab  = (const int*)d_in[2];
  float* out = (float*)d_out;

  size_t recB   = (size_t)NIMG * HWPX * sizeof(u64);         // 16.78 MB
  size_t partB  = (size_t)NIMG * NGRP * NSPLIT * 8 * NB * 4; // 16.78 MB
  size_t pstatB = (size_t)PREP_BLOCKS * 96 * sizeof(float);  //  0.20 MB
  size_t accB   = (size_t)NIMG * ACC_STRIDE * sizeof(double);
  size_t pairB  = 128 * 4 * sizeof(float);
  bool full = ws_size >= recB + partB + pstatB + accB + pairB;

  char* ws = (char*)d_ws;
  if (full) {
    u64*      rec   = (u64*)ws;
    unsigned* part  = (unsigned*)(ws + recB);
    float*    pstat = (float*)(ws + recB + partB);
    double*   accd  = (double*)(ws + recB + partB + pstatB);
    float*    pairinfo = (float*)(ws + recB + partB + pstatB + accB);
    k_prep<true><<<PREP_BLOCKS,1024,0,stream>>>(pred, inst, lab, rec, pstat);
    k_fin<<<NIMG,128,0,stream>>>(pstat, accd, pairinfo);
    k_hist<<<NIMG*NGRP*NSPLIT,1024,0,stream>>>(rec, pairinfo, part, accd);
    k_scan<<<128,1024,0,stream>>>(part, pairinfo, accd);
    k_final<<<1,64,0,stream>>>(accd, out);
  } else {
    float*    pstat = (float*)ws;
    double*   accd  = (double*)(ws + pstatB);
    float*    pairinfo = (float*)(ws + pstatB + accB);
    k_prep<false><<<PREP_BLOCKS,1024,0,stream>>>(pred, inst, lab, nullptr, pstat);
    k_fin<<<NIMG,128,0,stream>>>(pstat, accd, pairinfo);
    size_t lds18 = ((size_t)2*4097 + 2048)*4 + 128;
    k_lov_old<<<128,1024,lds18,stream>>>(pred, inst, lab, pairinfo, accd);
    k_final<<<1,64,0,stream>>>(accd, out);
  }
}

// Round 14
// 65.898 us; speedup vs baseline: 1.0192x; 1.0192x over previous
//
#include <hip/hip_runtime.h>
#include <hip/hip_fp16.h>
#include <math.h>

#define HWPX 262144   // 512*512
#define NIMG 8
#define ACC_STRIDE 96
#define NB 1024       // histogram bins (e-space for P, z-space for Q)
#define ZMAX 8.0f
#define NSPLIT 16
#define NGRP 2
#define PREP_BLOCKS 256   // 32 blocks/image, 1024 thr, 8 px/thread scalar (R10 best)
// accd layout per image (doubles):
// [80] bg_seed, [81] fit_seed(acc), [82] inst_loss(acc), [83] var_loss, [84] obj

typedef unsigned long long u64;

__device__ __forceinline__ float tanh_fast(float x) {
  float t = __expf(2.0f * x);
  return 1.0f - __fdividef(2.0f, t + 1.0f);
}
__device__ __forceinline__ float sigmoid_fast(float x) {
  return __fdividef(1.0f, 1.0f + __expf(-x));
}

// ---------- pass 1: k_lov-shaped streaming (1024 thr, scalar loads, 8-iter loop) ----------
template<bool PACK>
__global__ __launch_bounds__(1024) void k_prep(const float* __restrict__ pred,
    const int* __restrict__ inst, const int* __restrict__ lab,
    u64* __restrict__ rec, float* __restrict__ part)
{
  __shared__ float s[8][83];   // 8 replicas, stride 83 (coprime with 32 banks)
  int t = threadIdx.x;
  for (int i = t; i < 8*83; i += 1024) (&s[0][0])[i] = 0.0f;
  __syncthreads();
  int bid = blockIdx.x;
  int b = bid >> 5;                 // 32 blocks per image
  int chunk = bid & 31;             // 8192 px per block
  const float* pb = pred + (size_t)b*4*HWPX;
  size_t ib = (size_t)b*HWPX;
  int r = t & 7;
  float bg = 0.0f;
  #pragma unroll
  for (int j = 0; j < 8; ++j) {
    int px = (chunk << 13) + (j << 10) + t;
    float X = pb[px];
    float Y = pb[HWPX + px];
    float Gv = pb[2*HWPX + px];
    float Q = pb[3*HWPX + px];
    int L = lab[ib + px];
    int I = inst[ib + px];
    int w = px & 511, h = px >> 9;
    float xm = (float)w * (1.0f/1023.0f), ym = (float)h * (1.0f/1023.0f);
    float sd = sigmoid_fast(Q);
    int mid = (L == 1 && (unsigned)(I-1) < 16u) ? I : 0;
    if (PACK) {
      float ex = tanh_fast(X) + xm;
      float ey = tanh_fast(Y) + ym;
      rec[ib + px] = (u64)__half_as_ushort(__float2half(ex))
                   | ((u64)__half_as_ushort(__float2half(ey)) << 16)
                   | ((u64)__half_as_ushort(__float2half(sd)) << 32)
                   | ((u64)mid << 48);
    }
    if (L == 0) {
      bg += sd*sd;
    } else if (mid) {
      int k = mid - 1;
      atomicAdd(&s[r][k], 1.0f);
      atomicAdd(&s[r][16+k], xm);
      atomicAdd(&s[r][32+k], ym);
      atomicAdd(&s[r][48+k], Gv);
      atomicAdd(&s[r][64+k], Gv*Gv);
    }
  }
  #pragma unroll
  for (int o = 32; o > 0; o >>= 1) bg += __shfl_down(bg, o);
  if ((t & 63) == 0) atomicAdd(&s[0][80], bg);
  __syncthreads();
  if (t < 96) {
    float v = 0.0f;
    if (t < 81) {
      #pragma unroll
      for (int rr = 0; rr < 8; ++rr) v += s[rr][t];
    }
    part[(size_t)bid*96 + t] = v;
  }
}

// ---------- pass 1b: reduce 32 partials/image, finalize pairinfo + accd ----------
__global__ __launch_bounds__(128) void k_fin(const float* __restrict__ part,
    double* __restrict__ accd, float* __restrict__ pairinfo)
{
  __shared__ float red[96];
  int t = threadIdx.x, b = blockIdx.x;
  if (t < 96) {
    float v = 0.0f;
    const float* pp = part + (size_t)b*32*96 + t;
    #pragma unroll 8
    for (int blk = 0; blk < 32; ++blk) v += pp[(size_t)blk*96];
    red[t] = v;
  }
  __syncthreads();
  if (t < 16) {
    float cnt = red[t];
    float safe = cnt > 0.0f ? cnt : 1.0f;
    float sm = red[48+t] / safe;
    float4 pi = make_float4(red[16+t]/safe, red[32+t]/safe, __expf(10.0f*sm), cnt);
    ((float4*)pairinfo)[b*16 + t] = pi;
  }
  if (t == 0) {
    double vs = 0.0; float np = 0.0f;
    for (int k2 = 0; k2 < 16; ++k2) {
      float cnt = red[k2];
      if (cnt > 0.0f) {
        np += 1.0f;
        float ssg = red[48+k2];
        float var = (red[64+k2] - ssg*ssg/cnt) / cnt;
        if (var < 0.0f) var = 0.0f;
        vs += (double)var;
      }
    }
    double* ab = accd + (size_t)b*ACC_STRIDE;
    ab[80] = (double)red[80];
    ab[81] = 0.0;
    ab[82] = 0.0;
    ab[83] = vs;
    ab[84] = np > 1.0f ? (double)np : 1.0;
  }
}

// ---------- pass 2: 8-inst histograms, scalar rec loads, 16-iter loop ----------
__global__ __launch_bounds__(1024) void k_hist(const u64* __restrict__ rec,
    const float* __restrict__ pairinfo,
    unsigned* __restrict__ partial, double* __restrict__ accd)
{
  __shared__ unsigned hist[8*NB];   // 32 KB, P<<16 at e-bin, Q at z-bin
  __shared__ float redf[16];
  int t = threadIdx.x, bid = blockIdx.x;
  int b = bid & 7;                  // XCD-local image
  int rr = bid >> 3;
  int g = rr & 1;                   // instance group
  int s = rr >> 1;                  // pixel split 0..15
  for (int i = t; i < 8*NB; i += 1024) hist[i] = 0u;
  float cx[8], cy[8], se[8], s128[8];
  #pragma unroll
  for (int j = 0; j < 8; ++j) {
    float4 pi = ((const float4*)pairinfo)[b*16 + g*8 + j];
    cx[j] = pi.x; cy[j] = pi.y; se[j] = pi.z; s128[j] = pi.z * ((float)NB/ZMAX);
  }
  __syncthreads();
  size_t base = (size_t)b*HWPX + (size_t)s*(HWPX/NSPLIT);
  float fit = 0.0f;
  #pragma unroll 2
  for (int it = 0; it < HWPX/NSPLIT/1024; ++it) {   // 16 iterations, scalar u64
    size_t px = base + it*1024 + t;
    u64 v = rec[px];
    float ex = __half2float(__ushort_as_half((unsigned short)(v & 0xffffu)));
    float ey = __half2float(__ushort_as_half((unsigned short)((v >> 16) & 0xffffu)));
    float sd = __half2float(__ushort_as_half((unsigned short)((v >> 32) & 0xffffu)));
    int rel = (int)(v >> 48) - 1 - g*8;
    #pragma unroll
    for (int j = 0; j < 8; ++j) {
      float dx = ex - cx[j], dy = ey - cy[j];
      float d2 = fmaf(dx, dx, dy*dy);
      int key; unsigned add;
      if (rel == j) {                       // positive (rare)
        float d = __expf(-d2 * se[j]);
        float e = fmaf(-2.0f, d, 2.0f);
        int kk = (int)(e * (float)(NB/2));
        key = kk > NB-1 ? NB-1 : kk;
        add = 0x10000u;
        float df = sd - d; fit += df*df;
      } else {                              // negative: z-bin, no exp
        key = (int)fminf(d2 * s128[j], (float)(NB-1));
        add = 1u;
      }
      atomicAdd(&hist[j*NB + key], add);
    }
  }
  #pragma unroll
  for (int o = 32; o > 0; o >>= 1) fit += __shfl_down(fit, o);
  if ((t & 63) == 0) redf[t >> 6] = fit;
  __syncthreads();
  if (t == 0) {
    float ft = 0.0f;
    for (int i = 0; i < 16; ++i) ft += redf[i];
    atomicAdd(&accd[(size_t)b*ACC_STRIDE + 81], (double)ft);
  }
  unsigned* pp = partial + (size_t)((b*NGRP + g)*NSPLIT + s)*(8*NB);
  for (int i = t; i < 8*NB; i += 1024) pp[i] = hist[i];
}

// ---------- pass 3: merge partials, z->e, descending scan + Lovasz integral ----------
__global__ __launch_bounds__(1024) void k_scan(const unsigned* __restrict__ partial,
    const float* __restrict__ pairinfo, double* __restrict__ accd)
{
  __shared__ unsigned sp[NB], sq[NB];
  __shared__ float red[16];
  int t = threadIdx.x, bid = blockIdx.x;
  int b = bid >> 4, k = bid & 15;
  int g = k >> 3, j8 = k & 7;
  float G = pairinfo[(b*16 + k)*4 + 3];
  if (G <= 0.0f) return;   // absent instance (uniform block exit)
  sq[t] = 0u;
  __syncthreads();
  unsigned p = 0, q = 0;
  const unsigned* basep = partial + (size_t)((b*NGRP + g)*NSPLIT)*(8*NB) + j8*NB + t;
  #pragma unroll 4
  for (int s2 = 0; s2 < NSPLIT; ++s2) {
    unsigned h = basep[(size_t)s2*(8*NB)];
    p += h >> 16; q += h & 0xffffu;
  }
  // q is a z-bin count: convert to e-bin (e = 2*exp(-z_mid))
  float zmid = (t + 0.5f) * (ZMAX/NB);
  float ev = 2.0f * __expf(-zmid);
  int eb = (int)(ev * (float)(NB/2));
  if (eb > NB-1) eb = NB-1;
  if (q) atomicAdd(&sq[eb], q);
  __syncthreads();
  unsigned qe = sq[t];
  __syncthreads();
  int j = (NB-1) - t;          // descending-e rank
  sp[j] = p; sq[j] = qe;
  __syncthreads();
  for (int off = 1; off < NB; off <<= 1) {
    unsigned vp = 0, vq = 0;
    if (j >= off) { vp = sp[j-off]; vq = sq[j-off]; }
    __syncthreads();
    sp[j] += vp; sq[j] += vq;
    __syncthreads();
  }
  float A  = (float)(sp[j] - p);    // positives strictly above my e-bin
  float Bn = (float)(sq[j] - qe);   // negatives strictly above my e-bin
  float val = (t + 0.5f) * (2.0f/NB);
  float pf = (float)p, qf = (float)qe;
  float Jb = (A + Bn) / (G + Bn);
  float Ja = (A + Bn + pf + qf) / (G + Bn + qf);
  float contrib = val * (Ja - Jb);
  #pragma unroll
  for (int o = 32; o > 0; o >>= 1) contrib += __shfl_down(contrib, o);
  if ((t & 63) == 0) red[t >> 6] = contrib;
  __syncthreads();
  if (t == 0) {
    float tot = 0.0f;
    for (int i = 0; i < 16; ++i) tot += red[i];
    atomicAdd(&accd[(size_t)b*ACC_STRIDE + 82], (double)tot);
  }
}

// ---------- fallback: proven round-1 kernel (recompute path, SHIFT=18) ----------
__global__ __launch_bounds__(1024) void k_lov_old(const float* __restrict__ pred,
    const int* __restrict__ inst, const int* __restrict__ lab,
    const float* __restrict__ pairinfo, double* __restrict__ accd)
{
  constexpr int SHIFT = 18;
  constexpr int NBB = (0x40000000 >> SHIFT) + 1;
  extern __shared__ unsigned char smem[];
  unsigned* histP = reinterpret_cast<unsigned*>(smem);
  unsigned* histQ = histP + NBB;
  unsigned* scanP = histQ + NBB;
  unsigned* scanQ = scanP + 1024;
  float* red  = reinterpret_cast<float*>(scanQ + 1024);
  float* redf = red + 16;
  int t = threadIdx.x, bid = blockIdx.x;
  int b = bid >> 4, k = bid & 15;
  float4 pi = reinterpret_cast<const float4*>(pairinfo)[bid];
  float cx = pi.x, cy = pi.y, sexp = pi.z, G = pi.w;
  if (G <= 0.0f) return;
  for (int i = t; i < 2*NBB; i += 1024) histP[i] = 0u;
  __syncthreads();
  size_t ib = (size_t)b * HWPX;
  const float* pb = pred + (size_t)b * 4 * HWPX;
  const int target = k + 1;
  float fit = 0.0f;
  for (int j = 0; j < HWPX/1024; ++j) {
    int px = (j << 10) + t;
    int h = px >> 9, w = px & 511;
    float ex = tanhf(pb[px]) + w*(1.0f/1023.0f);
    float ey = tanhf(pb[HWPX+px]) + h*(1.0f/1023.0f);
    float sd = 1.0f/(1.0f + __expf(-pb[3*HWPX+px]));
    int lv = lab[ib+px], iv = inst[ib+px];
    float dx = ex - cx, dy = ey - cy;
    float d = __expf(-sexp * (dx*dx + dy*dy));
    bool m = (lv == 1) && (iv == target);
    float e = m ? fmaf(-2.0f, d, 2.0f) : 2.0f * d;
    unsigned key = __float_as_uint(e) >> SHIFT;
    atomicAdd(m ? &histP[key] : &histQ[key], 1u);
    if (m) { float df = sd - d; fit += df*df; }
  }
  #pragma unroll
  for (int o = 32; o > 0; o >>= 1) fit += __shfl_down(fit, o);
  if ((t & 63) == 0) redf[t >> 6] = fit;
  __syncthreads();
  constexpr int CB = NBB / 1024;
  int start = (NBB - 1) - t * CB;
  int nk = (t == 1023) ? (CB + 1) : CB;
  unsigned lp = 0, lq = 0;
  for (int i = 0; i < nk; ++i) { lp += histP[start-i]; lq += histQ[start-i]; }
  scanP[t] = lp; scanQ[t] = lq;
  __syncthreads();
  for (int off = 1; off < 1024; off <<= 1) {
    unsigned vp = 0, vq = 0;
    if (t >= off) { vp = scanP[t-off]; vq = scanQ[t-off]; }
    __syncthreads();
    scanP[t] += vp; scanQ[t] += vq;
    __syncthreads();
  }
  float A  = (float)(scanP[t] - lp);
  float Bn = (float)(scanQ[t] - lq);
  float contrib = 0.0f;
  for (int i = 0; i < nk; ++i) {
    int kk = start - i;
    unsigned p = histP[kk], q = histQ[kk];
    if (p | q) {
      float lo = __uint_as_float((unsigned)kk << SHIFT);
      float hi = __uint_as_float((unsigned)(kk+1) << SHIFT);
      float valv = 0.5f*(lo+hi);
      if (valv > 2.0f) valv = 2.0f;
      float pq = (float)(p + q), qf = (float)q;
      float Jb = (A + Bn) / (G + Bn);
      float Ja = (A + Bn + pq) / (G + Bn + qf);
      contrib += valv * (Ja - Jb);
      A += (float)p; Bn += qf;
    }
  }
  #pragma unroll
  for (int o = 32; o > 0; o >>= 1) contrib += __shfl_down(contrib, o);
  if ((t & 63) == 0) red[t >> 6] = contrib;
  __syncthreads();
  if (t == 0) {
    float tot = 0.0f, ft = 0.0f;
    for (int i = 0; i < 16; ++i) { tot += red[i]; ft += redf[i]; }
    atomicAdd(&accd[(size_t)b*ACC_STRIDE + 82], (double)tot);
    atomicAdd(&accd[(size_t)b*ACC_STRIDE + 81], (double)ft);
  }
}

__global__ void k_final(const double* __restrict__ accd, float* __restrict__ out)
{
  int t = threadIdx.x;
  double lb = 0.0;
  if (t < NIMG) {
    const double* ab = accd + (size_t)t*ACC_STRIDE;
    lb = (ab[82] + 10.0*ab[83]) / ab[84] + (ab[80] + ab[81]) * (1.0/(double)HWPX);
  }
  #pragma unroll
  for (int o = 4; o > 0; o >>= 1) lb += __shfl_down(lb, o);
  if (t == 0) out[0] = (float)(lb * 0.125);
}

extern "C" void kernel_launch(void* const* d_in, const int* in_sizes, int n_in,
                              void* d_out, int out_size, void* d_ws, size_t ws_size,
                              hipStream_t stream)
{
  const float* pred = (const float*)d_in[0];
  const int*   inst = (const int*)d_in[1];
  const int*   lab  = (const int*)d_in[2];
  float* out = (float*)d_out;

  size_t recB   = (size_t)NIMG * HWPX * sizeof(u64);         // 16.78 MB
  size_t partB  = (size_t)NIMG * NGRP * NSPLIT * 8 * NB * 4; //  8.39 MB
  size_t pstatB = (size_t)PREP_BLOCKS * 96 * sizeof(float);  //  0.10 MB
  size_t accB   = (size_t)NIMG * ACC_STRIDE * sizeof(double);
  size_t pairB  = 128 * 4 * sizeof(float);
  bool full = ws_size >= recB + partB + pstatB + accB + pairB;

  char* ws = (char*)d_ws;
  if (full) {
    u64*      rec   = (u64*)ws;
    unsigned* part  = (unsigned*)(ws + recB);
    float*    pstat = (float*)(ws + recB + partB);
    double*   accd  = (double*)(ws + recB + partB + pstatB);
    float*    pairinfo = (float*)(ws + recB + partB + pstatB + accB);
    k_prep<true><<<PREP_BLOCKS,1024,0,stream>>>(pred, inst, lab, rec, pstat);
    k_fin<<<NIMG,128,0,stream>>>(pstat, accd, pairinfo);
    k_hist<<<NIMG*NGRP*NSPLIT,1024,0,stream>>>(rec, pairinfo, part, accd);
    k_scan<<<128,1024,0,stream>>>(part, pairinfo, accd);
    k_final<<<1,64,0,stream>>>(accd, out);
  } else {
    float*    pstat = (float*)ws;
    double*   accd  = (double*)(ws + pstatB);
    float*    pairinfo = (float*)(ws + pstatB + accB);
    k_prep<false><<<PREP_BLOCKS,1024,0,stream>>>(pred, inst, lab, nullptr, pstat);
    k_fin<<<NIMG,128,0,stream>>>(pstat, accd, pairinfo);
    size_t lds18 = ((size_t)2*4097 + 2048)*4 + 128;
    k_lov_old<<<128,1024,lds18,stream>>>(pred, inst, lab, pairinfo, accd);
    k_final<<<1,64,0,stream>>>(accd, out);
  }
}